// Round 9
// baseline (1002.066 us; speedup 1.0000x reference)
//
#include <hip/hip_runtime.h>
#include <math.h>

#define N_NODES 65536
#define NPG     4096
#define D_IN    34
#define EMB     34
#define S_DIM   4
#define P_DIM   22
#define CONCAT  78      // EMB + 2*P_DIM
#define WIDTH   126
#define KNN     8
#define HPAD    24      // padded h row (22 -> 24)
#define EPAD    36      // padded emb row (34 -> 36)
#define TILE    1024    // j-tile staged in LDS
#define NSPLIT  16      // lanes per node
#define FBIG    3.4e38f
#define ASTR    65      // sA col stride (bank-spread for final projection)
#define WFSTR   9       // sWf row stride (9 coprime 32 -> conflict-free)

__device__ __forceinline__ float elu1(float v) {
    return v > 0.f ? v : expm1f(v);
}

__device__ __forceinline__ bool lexlt(float da, int ja, float db, int jb) {
    return (da < db) || (da == db && ja < jb);
}

// branchless insert of (dd,jj) into sorted-desc depth-4 (slot 0 = worst kept).
__device__ __forceinline__ void ins4(float (&d)[4], int (&ix)[4], float dd, int jj) {
    const bool s0 = dd < d[0];
    d[0] = s0 ? dd : d[0]; ix[0] = s0 ? jj : ix[0];
#pragma unroll
    for (int r = 0; r < 3; ++r) {
        const bool s = d[r] < d[r + 1];
        const float a = s ? d[r + 1] : d[r], b = s ? d[r] : d[r + 1];
        const int   x = s ? ix[r + 1] : ix[r], y = s ? ix[r] : ix[r + 1];
        d[r] = a; d[r + 1] = b; ix[r] = x; ix[r + 1] = y;
    }
}

// branchless insert into sorted-desc depth-8 (fixup path; exact for 16-way split)
__device__ __forceinline__ void ins8(float (&d)[8], int (&ix)[8], float dd, int jj) {
    const bool s0 = dd < d[0];
    d[0] = s0 ? dd : d[0]; ix[0] = s0 ? jj : ix[0];
#pragma unroll
    for (int r = 0; r < 7; ++r) {
        const bool s = d[r] < d[r + 1];
        const float a = s ? d[r + 1] : d[r], b = s ? d[r] : d[r + 1];
        const int   x = s ? ix[r + 1] : ix[r], y = s ? ix[r] : ix[r + 1];
        d[r] = a; d[r + 1] = b; ix[r] = x; ix[r + 1] = y;
    }
}

// bitonic cleaner: sort a bitonic 8-seq desc by lex (d,j)
__device__ __forceinline__ void clean8(float (&md)[8], int (&mj)[8]) {
#define CASL(i, k) { const bool sw = lexlt(md[i], mj[i], md[k], mj[k]); \
    const float a = sw ? md[k] : md[i], b = sw ? md[i] : md[k]; \
    const int   x = sw ? mj[k] : mj[i], y = sw ? mj[i] : mj[k]; \
    md[i] = a; md[k] = b; mj[i] = x; mj[k] = y; }
    CASL(0,4) CASL(1,5) CASL(2,6) CASL(3,7)
    CASL(0,2) CASL(1,3) CASL(4,6) CASL(5,7)
    CASL(0,1) CASL(2,3) CASL(4,5) CASL(6,7)
#undef CASL
}

// keep 8 lex-smallest of mine(sorted desc) + xor-m partner's, re-sorted desc
__device__ __forceinline__ void merge8(float (&md)[8], int (&mj)[8], int m) {
    float pd[8]; int pj[8];
#pragma unroll
    for (int i = 0; i < 8; ++i) { pd[i] = __shfl_xor(md[i], m); pj[i] = __shfl_xor(mj[i], m); }
#pragma unroll
    for (int i = 0; i < 8; ++i) {
        const bool lt = lexlt(md[i], mj[i], pd[7 - i], pj[7 - i]);
        const float nd = lt ? md[i] : pd[7 - i];
        const int   nj = lt ? mj[i] : pj[7 - i];
        md[i] = nd; mj[i] = nj;
    }
    clean8(md, mj);
}

// ---------------------------------------------------------------------------
// s = emb @ Ws + bs   [N,4];   h = emb @ Wh + bh   [N,22] (stored padded to 24)
// Also zeroes the flagged-node counter.
// ---------------------------------------------------------------------------
__global__ __launch_bounds__(256) void sh_kernel(
        const float* __restrict__ emb, int eld,
        const float* __restrict__ Ws, const float* __restrict__ bs,
        const float* __restrict__ Wh, const float* __restrict__ bh,
        float* __restrict__ s_out, float* __restrict__ h_out,
        int* __restrict__ fcnt) {
    if (blockIdx.x == 0 && threadIdx.x == 0) fcnt[0] = 0;

    __shared__ float lWs[EMB * S_DIM];
    __shared__ float lWh[EMB * P_DIM];
    __shared__ float lbs[S_DIM];
    __shared__ float lbh[P_DIM];
    for (int t = threadIdx.x; t < EMB * S_DIM; t += 256) lWs[t] = Ws[t];
    for (int t = threadIdx.x; t < EMB * P_DIM; t += 256) lWh[t] = Wh[t];
    if (threadIdx.x < S_DIM) lbs[threadIdx.x] = bs[threadIdx.x];
    if (threadIdx.x < P_DIM) lbh[threadIdx.x] = bh[threadIdx.x];
    __syncthreads();

    const int n = blockIdx.x * 256 + threadIdx.x;
    const float* __restrict__ row = emb + (size_t)n * eld;
    float e[EMB];
#pragma unroll
    for (int r = 0; r < EMB; ++r) e[r] = row[r];

    float s[S_DIM], h[P_DIM];
#pragma unroll
    for (int c = 0; c < S_DIM; ++c) s[c] = lbs[c];
#pragma unroll
    for (int c = 0; c < P_DIM; ++c) h[c] = lbh[c];
#pragma unroll
    for (int r = 0; r < EMB; ++r) {
        const float er = e[r];
#pragma unroll
        for (int c = 0; c < S_DIM; ++c) s[c] = fmaf(er, lWs[r * S_DIM + c], s[c]);
#pragma unroll
        for (int c = 0; c < P_DIM; ++c) h[c] = fmaf(er, lWh[r * P_DIM + c], h[c]);
    }
    ((float4*)s_out)[n] = make_float4(s[0], s[1], s[2], s[3]);
    float* __restrict__ hr = h_out + (size_t)n * HPAD;
#pragma unroll
    for (int c = 0; c < P_DIM; ++c) hr[c] = h[c];
}

// ---------------------------------------------------------------------------
// kNN scan: 16 lanes/node, 2 nodes/thread, depth-4 lists, exact lex merge,
// soundness flag -> compacted worklist. grid = 2048, block = 256.
// ---------------------------------------------------------------------------
__global__ __launch_bounds__(256, 4) void grav_scan(
        const float* __restrict__ s_buf,
        float* __restrict__ knnd, int* __restrict__ knnj,
        int* __restrict__ fcnt, int* __restrict__ flist) {
    __shared__ float4 sl[TILE];           // 16 KB j-tile

    const int g     = blockIdx.x >> 7;
    const int chunk = blockIdx.x & 127;
    const int gbase = g * NPG;
    const int tid   = threadIdx.x;
    const int ql    = tid & 15;
    const int grp   = tid >> 4;
    const int nA    = gbase + chunk * 32 + grp * 2;
    const int nB    = nA + 1;

    const float4* __restrict__ sg = (const float4*)s_buf + gbase;
    float4 pre[4];
#pragma unroll
    for (int i = 0; i < 4; ++i) pre[i] = sg[tid + 256 * i];
    const float4 siA = ((const float4*)s_buf)[nA];
    const float4 siB = ((const float4*)s_buf)[nB];

    float dA[4], dB[4]; int jA[4], jB[4];
#pragma unroll
    for (int r = 0; r < 4; ++r) { dA[r] = FBIG; jA[r] = 0; dB[r] = FBIG; jB[r] = 0; }

#pragma unroll
    for (int i = 0; i < 4; ++i) sl[tid + 256 * i] = pre[i];
    __syncthreads();

    for (int t = 0; t < NPG / TILE; ++t) {
        if (t < NPG / TILE - 1) {
#pragma unroll
            for (int i = 0; i < 4; ++i)
                pre[i] = sg[(t + 1) * TILE + tid + 256 * i];
        }
        const int jb = t * TILE + ql;
#pragma unroll 4
        for (int k = 0; k < TILE / NSPLIT; ++k) {
            const float4 sj = sl[NSPLIT * k + ql];
            const int jj = jb + NSPLIT * k;
            {
                const float dx = siA.x - sj.x, dy = siA.y - sj.y;
                const float dz = siA.z - sj.z, dw = siA.w - sj.w;
                const float d2 = fmaf(dx, dx, fmaf(dy, dy, fmaf(dz, dz, dw * dw)));
                ins4(dA, jA, d2, jj);
            }
            {
                const float dx = siB.x - sj.x, dy = siB.y - sj.y;
                const float dz = siB.z - sj.z, dw = siB.w - sj.w;
                const float d2 = fmaf(dx, dx, fmaf(dy, dy, fmaf(dz, dz, dw * dw)));
                ins4(dB, jB, d2, jj);
            }
        }
        if (t < NPG / TILE - 1) {
            __syncthreads();
#pragma unroll
            for (int i = 0; i < 4; ++i) sl[tid + 256 * i] = pre[i];
            __syncthreads();
        }
    }

    const int lane = tid & 63;

    // ---- node A ----
    {
        float md[8]; int mj[8];
        float pd3 = __shfl_xor(dA[3], 1), pd2 = __shfl_xor(dA[2], 1);
        float pd1 = __shfl_xor(dA[1], 1), pd0 = __shfl_xor(dA[0], 1);
        int   pj3 = __shfl_xor(jA[3], 1), pj2 = __shfl_xor(jA[2], 1);
        int   pj1 = __shfl_xor(jA[1], 1), pj0 = __shfl_xor(jA[0], 1);
        md[0] = dA[0]; md[1] = dA[1]; md[2] = dA[2]; md[3] = dA[3];
        mj[0] = jA[0]; mj[1] = jA[1]; mj[2] = jA[2]; mj[3] = jA[3];
        md[4] = pd3; md[5] = pd2; md[6] = pd1; md[7] = pd0;
        mj[4] = pj3; mj[5] = pj2; mj[6] = pj1; mj[7] = pj0;
        clean8(md, mj);
        merge8(md, mj, 2);
        merge8(md, mj, 4);
        merge8(md, mj, 8);

        const bool lost = !lexlt(md[0], mj[0], dA[0], jA[0]);
        const unsigned long long bal = __ballot(lost);
        const bool flag = (((bal >> (lane & 48)) & 0xFFFFull) != 0ull);

        float ds = md[0]; int js = mj[0];
#pragma unroll
        for (int r = 1; r < 8; ++r) {
            const bool p = (ql == r);
            ds = p ? md[r] : ds; js = p ? mj[r] : js;
        }
        if (ql < 8) {
            knnd[(size_t)nA * 8 + ql] = ds;
            knnj[(size_t)nA * 8 + ql] = js;
        }
        if (ql == 0 && flag) {
            const int slot = atomicAdd(fcnt, 1);
            flist[slot] = nA;
        }
    }

    // ---- node B ----
    {
        float md[8]; int mj[8];
        float pd3 = __shfl_xor(dB[3], 1), pd2 = __shfl_xor(dB[2], 1);
        float pd1 = __shfl_xor(dB[1], 1), pd0 = __shfl_xor(dB[0], 1);
        int   pj3 = __shfl_xor(jB[3], 1), pj2 = __shfl_xor(jB[2], 1);
        int   pj1 = __shfl_xor(jB[1], 1), pj0 = __shfl_xor(jB[0], 1);
        md[0] = dB[0]; md[1] = dB[1]; md[2] = dB[2]; md[3] = dB[3];
        mj[0] = jB[0]; mj[1] = jB[1]; mj[2] = jB[2]; mj[3] = jB[3];
        md[4] = pd3; md[5] = pd2; md[6] = pd1; md[7] = pd0;
        mj[4] = pj3; mj[5] = pj2; mj[6] = pj1; mj[7] = pj0;
        clean8(md, mj);
        merge8(md, mj, 2);
        merge8(md, mj, 4);
        merge8(md, mj, 8);

        const bool lost = !lexlt(md[0], mj[0], dB[0], jB[0]);
        const unsigned long long bal = __ballot(lost);
        const bool flag = (((bal >> (lane & 48)) & 0xFFFFull) != 0ull);

        float ds = md[0]; int js = mj[0];
#pragma unroll
        for (int r = 1; r < 8; ++r) {
            const bool p = (ql == r);
            ds = p ? md[r] : ds; js = p ? mj[r] : js;
        }
        if (ql < 8) {
            knnd[(size_t)nB * 8 + ql] = ds;
            knnj[(size_t)nB * 8 + ql] = js;
        }
        if (ql == 0 && flag) {
            const int slot = atomicAdd(fcnt, 1);
            flist[slot] = nB;
        }
    }
}

// ---------------------------------------------------------------------------
// Fixup: exact rescan of the compacted flagged-node list (grid-strided).
// ---------------------------------------------------------------------------
__global__ __launch_bounds__(256, 4) void grav_fix(
        const float* __restrict__ s_buf,
        float* __restrict__ knnd, int* __restrict__ knnj,
        const int* __restrict__ fcnt, const int* __restrict__ flist) {
    const int cnt = fcnt[0];
    const int ql  = threadIdx.x & 15;
    const int ngroups = gridDim.x * 16;

    for (int idx = blockIdx.x * 16 + (threadIdx.x >> 4); idx < cnt; idx += ngroups) {
        const int node = flist[idx];
        const int gbase = node & ~(NPG - 1);
        const float4 si = ((const float4*)s_buf)[node];
        const float4* __restrict__ sg = (const float4*)s_buf + gbase;

        float fd[8]; int fj[8];
#pragma unroll
        for (int r = 0; r < 8; ++r) { fd[r] = FBIG; fj[r] = 0; }
#pragma unroll 4
        for (int k = 0; k < NPG / NSPLIT; ++k) {
            const int j = NSPLIT * k + ql;
            const float4 sj = sg[j];
            const float dx = si.x - sj.x, dy = si.y - sj.y;
            const float dz = si.z - sj.z, dw = si.w - sj.w;
            const float d2 = fmaf(dx, dx, fmaf(dy, dy, fmaf(dz, dz, dw * dw)));
            ins8(fd, fj, d2, j);
        }
        merge8(fd, fj, 1);
        merge8(fd, fj, 2);
        merge8(fd, fj, 4);
        merge8(fd, fj, 8);

        float ds = fd[0]; int js = fj[0];
#pragma unroll
        for (int r = 1; r < 8; ++r) {
            const bool p = (ql == r);
            ds = p ? fd[r] : ds; js = p ? fj[r] : js;
        }
        if (ql < 8) {
            knnd[(size_t)node * 8 + ql] = ds;
            knnj[(size_t)node * 8 + ql] = js;
        }
    }
}

// ---------------------------------------------------------------------------
// Gather + aggregate + fused output GEMM. 64 nodes/block, 4 lanes/node.
// ---------------------------------------------------------------------------
template <int ELD, bool TOUT>
__global__ __launch_bounds__(256, 4) void grav_gather(
        const float* __restrict__ emb_in,
        const float* __restrict__ h_buf,
        const float* __restrict__ knnd, const int* __restrict__ knnj,
        const float* __restrict__ Wo, const float* __restrict__ bo,
        float* __restrict__ out) {
    __shared__ float wot[EMB * 81];       // Wo^T, rows padded 78 -> 81
    __shared__ float bol[EMB];
    __shared__ float cc[64][49];          // per-node mean @0, max @24

    const int tid = threadIdx.x;
    const int q   = tid & 3;
    const int nl  = tid >> 2;
    const int node = blockIdx.x * 64 + nl;
    const int gbase = node & ~(NPG - 1);

    for (int t = tid; t < CONCAT * EMB; t += 256) {
        const int r = t / EMB, c = t % EMB;
        wot[c * 81 + r] = Wo[t];
    }
    if (tid < EMB) bol[tid] = bo[tid];

    const float da = knnd[(size_t)node * 8 + q];
    const float db = knnd[(size_t)node * 8 + 4 + q];
    const int   ja = knnj[(size_t)node * 8 + q];
    const int   jb = knnj[(size_t)node * 8 + 4 + q];
    const float wa = expf(-10.f * da);
    const float wb = expf(-10.f * db);
    const float4* __restrict__ ha = (const float4*)(h_buf + (size_t)(gbase + ja) * HPAD);
    const float4* __restrict__ hb = (const float4*)(h_buf + (size_t)(gbase + jb) * HPAD);

#pragma unroll
    for (int ch = 0; ch < 6; ++ch) {
        const float4 qa = ha[ch], qb = hb[ch];
        float sx = fmaf(wa, qa.x, wb * qb.x), sy = fmaf(wa, qa.y, wb * qb.y);
        float sz = fmaf(wa, qa.z, wb * qb.z), sw = fmaf(wa, qa.w, wb * qb.w);
        float mx = fmaxf(wa * qa.x, wb * qb.x), my = fmaxf(wa * qa.y, wb * qb.y);
        float mz = fmaxf(wa * qa.z, wb * qb.z), mw = fmaxf(wa * qa.w, wb * qb.w);
#pragma unroll
        for (int m = 1; m <= 2; m <<= 1) {
            sx += __shfl_xor(sx, m); sy += __shfl_xor(sy, m);
            sz += __shfl_xor(sz, m); sw += __shfl_xor(sw, m);
            mx = fmaxf(mx, __shfl_xor(mx, m)); my = fmaxf(my, __shfl_xor(my, m));
            mz = fmaxf(mz, __shfl_xor(mz, m)); mw = fmaxf(mw, __shfl_xor(mw, m));
        }
        if (q == (ch & 3)) {
            cc[nl][ch * 4 + 0] = sx * 0.125f; cc[nl][ch * 4 + 1] = sy * 0.125f;
            cc[nl][ch * 4 + 2] = sz * 0.125f; cc[nl][ch * 4 + 3] = sw * 0.125f;
            cc[nl][24 + ch * 4 + 0] = mx; cc[nl][24 + ch * 4 + 1] = my;
            cc[nl][24 + ch * 4 + 2] = mz; cc[nl][24 + ch * 4 + 3] = mw;
        }
    }
    __syncthreads();

    float e[EMB];
    const float* __restrict__ erow = emb_in + (size_t)node * ELD;
    if constexpr (ELD == 34) {
#pragma unroll
        for (int i = 0; i < 17; ++i) {
            const float2 v = ((const float2*)erow)[i];
            e[2 * i] = v.x; e[2 * i + 1] = v.y;
        }
    } else {
#pragma unroll
        for (int i = 0; i < 8; ++i) {
            const float4 v = ((const float4*)erow)[i];
            e[4 * i] = v.x; e[4 * i + 1] = v.y; e[4 * i + 2] = v.z; e[4 * i + 3] = v.w;
        }
        const float2 v = ((const float2*)erow)[16];
        e[32] = v.x; e[33] = v.y;
    }

#pragma unroll
    for (int m = 0; m < 9; ++m) {
        const int c = q + 4 * m;
        if (c < EMB) {
            const float* __restrict__ wr = &wot[c * 81];
            float acc = bol[c];
#pragma unroll
            for (int r = 0; r < EMB; ++r)   acc = fmaf(e[r], wr[r], acc);
#pragma unroll
            for (int p = 0; p < P_DIM; ++p) acc = fmaf(cc[nl][p], wr[34 + p], acc);
#pragma unroll
            for (int p = 0; p < P_DIM; ++p) acc = fmaf(cc[nl][24 + p], wr[56 + p], acc);
            if constexpr (TOUT)
                out[(size_t)c * N_NODES + node] = acc;
            else
                out[(size_t)node * EPAD + c] = acc;
        }
    }
}

// ---------------------------------------------------------------------------
// Fused 3-head MLP v2: single activation buffer (register round-trip per
// layer), L0 input straight from global, conflict-free final projection.
// Block = 512 thr (8 waves x 16 cols), 64 rows. LDS ~37 KB -> 4 blocks/CU.
// ---------------------------------------------------------------------------
__global__ __launch_bounds__(512, 6) void heads_fused(
        const float* __restrict__ emb2T,   // [34][N]
        const float* __restrict__ xin,
        float* __restrict__ outp,
        const float* __restrict__ W0a, const float* __restrict__ b0a,
        const float* __restrict__ Wha, const float* __restrict__ bha,
        const float* __restrict__ Wfa, const float* __restrict__ bfa,
        const float* __restrict__ W0b, const float* __restrict__ b0b,
        const float* __restrict__ Whb, const float* __restrict__ bhb,
        const float* __restrict__ Wfb, const float* __restrict__ bfb,
        const float* __restrict__ W0c, const float* __restrict__ b0c,
        const float* __restrict__ Whc, const float* __restrict__ bhc,
        const float* __restrict__ Wfc, const float* __restrict__ bfc) {
    __shared__ float sA[WIDTH * ASTR];    // 32.76 KB act [126][64+pad]
    __shared__ float sWf[128 * WFSTR];    // 4.5 KB final weights, stride 9

    const int tid  = threadIdx.x;
    const int head = blockIdx.x % 3;
    const int rowbase = (blockIdx.x / 3) * 64;
    const int lane = tid & 63;            // row within tile
    const int wave = __builtin_amdgcn_readfirstlane(tid >> 6);
    int colbase = wave * 16;
    if (colbase > WIDTH - 16) colbase = WIDTH - 16;   // wave 7: 110..125

    const float* W0 = head == 0 ? W0a : head == 1 ? W0b : W0c;
    const float* b0 = head == 0 ? b0a : head == 1 ? b0b : b0c;
    const float* Wh = head == 0 ? Wha : head == 1 ? Whb : Whc;
    const float* bh = head == 0 ? bha : head == 1 ? bhb : bhc;
    const float* Wf = head == 0 ? Wfa : head == 1 ? Wfb : Wfc;
    const float* bf = head == 0 ? bfa : head == 1 ? bfb : bfc;
    const int odim  = head == 0 ? 8 : head == 1 ? 4 : 1;
    const size_t ooff = head == 0 ? 0
                      : head == 1 ? (size_t)N_NODES * 8 : (size_t)N_NODES * 12;

    // stage Wf (zero-padded k in [126,128), stride 9)
    for (int t = tid; t < 128 * 8; t += 512) {
        const int k = t >> 3, o = t & 7;
        sWf[k * WFSTR + o] = (k < WIDTH && o < odim) ? Wf[k * odim + o] : 0.f;
    }

    float acc[16];

    // ---- L0: 34 -> 126 (input from global, coalesced + L1-hot) ----
#pragma unroll
    for (int o = 0; o < 16; ++o) acc[o] = b0[colbase + o];
#pragma unroll 2
    for (int k = 0; k < EMB; ++k) {
        const float xk = emb2T[(size_t)k * N_NODES + rowbase + lane];
        const float* __restrict__ wr = W0 + (size_t)k * WIDTH + colbase;
#pragma unroll
        for (int o = 0; o < 16; ++o) acc[o] = fmaf(xk, wr[o], acc[o]);
    }
    __syncthreads();   // sWf staging complete (and sA free to write)
#pragma unroll
    for (int o = 0; o < 16; ++o) sA[(colbase + o) * ASTR + lane] = elu1(acc[o]);
    __syncthreads();

    // ---- L1: 126 -> 126 (read all of sA, then write back in place) ----
#pragma unroll
    for (int o = 0; o < 16; ++o) acc[o] = bh[colbase + o];
#pragma unroll 2
    for (int k = 0; k < WIDTH; ++k) {
        const float xk = sA[k * ASTR + lane];
        const float* __restrict__ wr = Wh + (size_t)k * WIDTH + colbase;
#pragma unroll
        for (int o = 0; o < 16; ++o) acc[o] = fmaf(xk, wr[o], acc[o]);
    }
    __syncthreads();   // all reads of sA done
#pragma unroll
    for (int o = 0; o < 16; ++o) sA[(colbase + o) * ASTR + lane] = elu1(acc[o]);
    __syncthreads();

    // ---- L2: 126 -> 126 ----
#pragma unroll
    for (int o = 0; o < 16; ++o) acc[o] = bh[WIDTH + colbase + o];
#pragma unroll 2
    for (int k = 0; k < WIDTH; ++k) {
        const float xk = sA[k * ASTR + lane];
        const float* __restrict__ wr = Wh + (size_t)(WIDTH + k) * WIDTH + colbase;
#pragma unroll
        for (int o = 0; o < 16; ++o) acc[o] = fmaf(xk, wr[o], acc[o]);
    }
    __syncthreads();
#pragma unroll
    for (int o = 0; o < 16; ++o) sA[(colbase + o) * ASTR + lane] = elu1(acc[o]);
    __syncthreads();

    // ---- final: lane-strided k (k = lane, lane+64), full-wave reduce ----
    // wave w owns rows w*8 .. w*8+7 of the tile.
    const float xw0 = sWf[lane * WFSTR + 0], xw1 = sWf[(lane + 64) * WFSTR + 0];
#pragma unroll
    for (int r = 0; r < 8; ++r) {
        const int rowl = wave * 8 + r;
        const float xa0 = sA[lane * ASTR + rowl];                       // 2-way = free
        const float xa1 = (lane + 64 < WIDTH) ? sA[(lane + 64) * ASTR + rowl] : 0.f;
        float pa[8];
#pragma unroll
        for (int o = 0; o < 8; ++o) {
            const float w0 = (o == 0) ? xw0 : sWf[lane * WFSTR + o];
            const float w1 = (o == 0) ? xw1 : sWf[(lane + 64) * WFSTR + o];
            pa[o] = fmaf(xa0, w0, xa1 * w1);
        }
#pragma unroll
        for (int m = 1; m <= 32; m <<= 1) {
#pragma unroll
            for (int o = 0; o < 8; ++o) pa[o] += __shfl_xor(pa[o], m);
        }
        if (lane < odim) {
            float v = pa[0];
#pragma unroll
            for (int o = 1; o < 8; ++o) { const bool p = (lane == o); v = p ? pa[o] : v; }
            v += bf[lane];
            const int grow = rowbase + rowl;
            if (head == 1) v += xin[(size_t)grow * D_IN + 1 + lane];
            outp[ooff + (size_t)grow * odim + lane] = v;
        }
    }
}

// ---------------------------------------------------------------------------
extern "C" void kernel_launch(void* const* d_in, const int* in_sizes, int n_in,
                              void* d_out, int out_size, void* d_ws, size_t ws_size,
                              hipStream_t stream) {
    (void)in_sizes; (void)n_in; (void)out_size;

    const float* x   = (const float*)d_in[0];
    const float* cWs = (const float*)d_in[1];
    const float* cbs = (const float*)d_in[2];
    const float* cWh = (const float*)d_in[3];
    const float* cbh = (const float*)d_in[4];
    const float* cWo = (const float*)d_in[5];
    const float* cbo = (const float*)d_in[6];
    const float* hW0[3] = {(const float*)d_in[7],  (const float*)d_in[13], (const float*)d_in[19]};
    const float* hb0[3] = {(const float*)d_in[8],  (const float*)d_in[14], (const float*)d_in[20]};
    const float* hWh[3] = {(const float*)d_in[9],  (const float*)d_in[15], (const float*)d_in[21]};
    const float* hbh[3] = {(const float*)d_in[10], (const float*)d_in[16], (const float*)d_in[22]};
    const float* hWf[3] = {(const float*)d_in[11], (const float*)d_in[17], (const float*)d_in[23]};
    const float* hbf[3] = {(const float*)d_in[12], (const float*)d_in[18], (const float*)d_in[24]};
    float* outp = (float*)d_out;
    float* ws = (float*)d_ws;

    // workspace layout (floats)
    const size_t OFF_S   = 0;
    const size_t OFF_H   = OFF_S   + (size_t)N_NODES * 4;
    const size_t OFF_E1  = OFF_H   + (size_t)N_NODES * HPAD;
    const size_t OFF_E2T = OFF_E1  + (size_t)N_NODES * EPAD;
    const size_t OFF_KS  = OFF_E2T + (size_t)EMB * N_NODES;
    const size_t WS_END  = OFF_KS  + (size_t)N_NODES * 18;
    if (ws_size < WS_END * sizeof(float)) return;

    float* s_buf  = ws + OFF_S;
    float* h_buf  = ws + OFF_H;
    float* emb1   = ws + OFF_E1;
    float* emb2T  = ws + OFF_E2T;
    float* knnd   = ws + OFF_KS;                             // N*8 floats
    int*   knnj   = (int*)(knnd + (size_t)N_NODES * 8);      // N*8 ints
    int*   flist  = (int*)(knnd + (size_t)N_NODES * 16);     // N ints
    int*   fcnt   = (int*)(knnd + (size_t)N_NODES * 17);     // 1 int

    // ---- GravNet conv 1 (emb = x, row-major out) ----
    sh_kernel<<<256, 256, 0, stream>>>(x, D_IN, cWs, cbs, cWh, cbh, s_buf, h_buf, fcnt);
    grav_scan<<<2048, 256, 0, stream>>>(s_buf, knnd, knnj, fcnt, flist);
    grav_fix<<<256, 256, 0, stream>>>(s_buf, knnd, knnj, fcnt, flist);
    grav_gather<34, false><<<1024, 256, 0, stream>>>(x, h_buf, knnd, knnj, cWo, cbo, emb1);

    // ---- GravNet conv 2 (transposed out for heads) ----
    sh_kernel<<<256, 256, 0, stream>>>(emb1, EPAD, cWs + EMB * S_DIM, cbs + S_DIM,
                                       cWh + EMB * P_DIM, cbh + P_DIM, s_buf, h_buf, fcnt);
    grav_scan<<<2048, 256, 0, stream>>>(s_buf, knnd, knnj, fcnt, flist);
    grav_fix<<<256, 256, 0, stream>>>(s_buf, knnd, knnj, fcnt, flist);
    grav_gather<36, true><<<1024, 256, 0, stream>>>(emb1, h_buf, knnd, knnj,
                                                    cWo + CONCAT * EMB, cbo + EMB, emb2T);

    // ---- heads: one fused dispatch for all 3 MLPs ----
    heads_fused<<<3072, 512, 0, stream>>>(
        emb2T, x, outp,
        hW0[0], hb0[0], hWh[0], hbh[0], hWf[0], hbf[0],
        hW0[1], hb0[1], hWh[1], hbh[1], hWf[1], hbf[1],
        hW0[2], hb0[2], hWh[2], hbh[2], hWf[2], hbf[2]);
}

// Round 10
// 776.019 us; speedup vs baseline: 1.2913x; 1.2913x over previous
//
#include <hip/hip_runtime.h>
#include <math.h>

#define N_NODES 65536
#define NPG     4096
#define D_IN    34
#define EMB     34
#define S_DIM   4
#define P_DIM   22
#define CONCAT  78      // EMB + 2*P_DIM
#define WIDTH   126
#define KNN     8
#define HPAD    24      // padded h row (22 -> 24)
#define EPAD    36      // padded emb row (34 -> 36)
#define TILE    1024    // j-tile staged in LDS
#define NSPLIT  16      // lanes per node
#define FBIG    3.4e38f
#define ASTR    133     // heads sA col stride (133%32=5, coprime -> conflict-free)
#define WFSTR   9       // sWf row stride (9 coprime 32 -> conflict-free)
#define TRUNCM  0xFFFFF000u

__device__ __forceinline__ float elu1(float v) {
    return v > 0.f ? v : expm1f(v);
}

__device__ __forceinline__ bool lexlt(float da, int ja, float db, int jb) {
    return (da < db) || (da == db && ja < jb);
}

// ---- packed-key helpers (key = d2bits[31:12] | k[8b]<<4 | lane[4b]) ----
// u32 order == (d2 asc, j asc) up to 12-bit truncation; ambiguity flagged.

__device__ __forceinline__ void ins4u(unsigned (&k)[4], unsigned key) {
    unsigned c = min(key, k[0]);          // k[0] = worst kept (list sorted desc)
#pragma unroll
    for (int r = 3; r >= 1; --r) {
        const unsigned hi = max(k[r], c);
        k[r] = min(k[r], c);
        c = hi;
    }
    k[0] = c;
}

__device__ __forceinline__ void clean8u(unsigned (&k)[8]) {
#define CASU(i, j2) { const unsigned hi = max(k[i], k[j2]); \
    const unsigned lo = min(k[i], k[j2]); k[i] = hi; k[j2] = lo; }
    CASU(0,4) CASU(1,5) CASU(2,6) CASU(3,7)
    CASU(0,2) CASU(1,3) CASU(4,6) CASU(5,7)
    CASU(0,1) CASU(2,3) CASU(4,5) CASU(6,7)
#undef CASU
}

__device__ __forceinline__ void merge8u(unsigned (&k)[8], int m) {
    unsigned p[8];
#pragma unroll
    for (int i = 0; i < 8; ++i) p[i] = (unsigned)__shfl_xor((int)k[i], m);
#pragma unroll
    for (int i = 0; i < 8; ++i) k[i] = min(k[i], p[7 - i]);
    clean8u(k);
}

// ---- exact (d,j) helpers (fixup path) ----
__device__ __forceinline__ void ins8(float (&d)[8], int (&ix)[8], float dd, int jj) {
    const bool s0 = dd < d[0];
    d[0] = s0 ? dd : d[0]; ix[0] = s0 ? jj : ix[0];
#pragma unroll
    for (int r = 0; r < 7; ++r) {
        const bool s = d[r] < d[r + 1];
        const float a = s ? d[r + 1] : d[r], b = s ? d[r] : d[r + 1];
        const int   x = s ? ix[r + 1] : ix[r], y = s ? ix[r] : ix[r + 1];
        d[r] = a; d[r + 1] = b; ix[r] = x; ix[r + 1] = y;
    }
}

__device__ __forceinline__ void clean8(float (&md)[8], int (&mj)[8]) {
#define CASL(i, k) { const bool sw = lexlt(md[i], mj[i], md[k], mj[k]); \
    const float a = sw ? md[k] : md[i], b = sw ? md[i] : md[k]; \
    const int   x = sw ? mj[k] : mj[i], y = sw ? mj[i] : mj[k]; \
    md[i] = a; md[k] = b; mj[i] = x; mj[k] = y; }
    CASL(0,4) CASL(1,5) CASL(2,6) CASL(3,7)
    CASL(0,2) CASL(1,3) CASL(4,6) CASL(5,7)
    CASL(0,1) CASL(2,3) CASL(4,5) CASL(6,7)
#undef CASL
}

__device__ __forceinline__ void merge8(float (&md)[8], int (&mj)[8], int m) {
    float pd[8]; int pj[8];
#pragma unroll
    for (int i = 0; i < 8; ++i) { pd[i] = __shfl_xor(md[i], m); pj[i] = __shfl_xor(mj[i], m); }
#pragma unroll
    for (int i = 0; i < 8; ++i) {
        const bool lt = lexlt(md[i], mj[i], pd[7 - i], pj[7 - i]);
        const float nd = lt ? md[i] : pd[7 - i];
        const int   nj = lt ? mj[i] : pj[7 - i];
        md[i] = nd; mj[i] = nj;
    }
    clean8(md, mj);
}

// ---------------------------------------------------------------------------
// s = emb @ Ws + bs   [N,4];   h = emb @ Wh + bh   [N,22] (stored padded to 24)
// Also zeroes the flagged-node counter.
// ---------------------------------------------------------------------------
__global__ __launch_bounds__(256) void sh_kernel(
        const float* __restrict__ emb, int eld,
        const float* __restrict__ Ws, const float* __restrict__ bs,
        const float* __restrict__ Wh, const float* __restrict__ bh,
        float* __restrict__ s_out, float* __restrict__ h_out,
        int* __restrict__ fcnt) {
    if (blockIdx.x == 0 && threadIdx.x == 0) fcnt[0] = 0;

    __shared__ float lWs[EMB * S_DIM];
    __shared__ float lWh[EMB * P_DIM];
    __shared__ float lbs[S_DIM];
    __shared__ float lbh[P_DIM];
    for (int t = threadIdx.x; t < EMB * S_DIM; t += 256) lWs[t] = Ws[t];
    for (int t = threadIdx.x; t < EMB * P_DIM; t += 256) lWh[t] = Wh[t];
    if (threadIdx.x < S_DIM) lbs[threadIdx.x] = bs[threadIdx.x];
    if (threadIdx.x < P_DIM) lbh[threadIdx.x] = bh[threadIdx.x];
    __syncthreads();

    const int n = blockIdx.x * 256 + threadIdx.x;
    const float* __restrict__ row = emb + (size_t)n * eld;
    float e[EMB];
#pragma unroll
    for (int r = 0; r < EMB; ++r) e[r] = row[r];

    float s[S_DIM], h[P_DIM];
#pragma unroll
    for (int c = 0; c < S_DIM; ++c) s[c] = lbs[c];
#pragma unroll
    for (int c = 0; c < P_DIM; ++c) h[c] = lbh[c];
#pragma unroll
    for (int r = 0; r < EMB; ++r) {
        const float er = e[r];
#pragma unroll
        for (int c = 0; c < S_DIM; ++c) s[c] = fmaf(er, lWs[r * S_DIM + c], s[c]);
#pragma unroll
        for (int c = 0; c < P_DIM; ++c) h[c] = fmaf(er, lWh[r * P_DIM + c], h[c]);
    }
    ((float4*)s_out)[n] = make_float4(s[0], s[1], s[2], s[3]);
    float* __restrict__ hr = h_out + (size_t)n * HPAD;
#pragma unroll
    for (int c = 0; c < P_DIM; ++c) hr[c] = h[c];
}

// ---------------------------------------------------------------------------
// kNN scan v2: packed u32 keys. 16 lanes/node, 2 nodes/thread, depth-4
// branchless u32 lists (7 ops/insert), exact-or-flagged merge.
// Sound flag: dropped x can exactly-beat kept y only if trunc(x)==trunc(W);
// flag if #(kept entries with trunc<=truncW) > 8 or any lane's worst-kept
// trunc <= truncW (covers unseen discards: all discards > lane worst-kept).
// ---------------------------------------------------------------------------
__global__ __launch_bounds__(256, 4) void grav_scan(
        const float* __restrict__ s_buf,
        int* __restrict__ knnj,
        int* __restrict__ fcnt, int* __restrict__ flist) {
    __shared__ float4 sl[TILE];           // 16 KB j-tile

    const int g     = blockIdx.x >> 7;
    const int chunk = blockIdx.x & 127;
    const int gbase = g * NPG;
    const int tid   = threadIdx.x;
    const int ql    = tid & 15;
    const int grp   = tid >> 4;
    const int nA    = gbase + chunk * 32 + grp * 2;
    const int nB    = nA + 1;

    const float4* __restrict__ sg = (const float4*)s_buf + gbase;
    float4 pre[4];
#pragma unroll
    for (int i = 0; i < 4; ++i) pre[i] = sg[tid + 256 * i];
    const float4 siA = ((const float4*)s_buf)[nA];
    const float4 siB = ((const float4*)s_buf)[nB];

    unsigned kA[4], kB[4];
#pragma unroll
    for (int r = 0; r < 4; ++r) { kA[r] = 0xFFFFFFFFu; kB[r] = 0xFFFFFFFFu; }

#pragma unroll
    for (int i = 0; i < 4; ++i) sl[tid + 256 * i] = pre[i];
    __syncthreads();

    for (int t = 0; t < NPG / TILE; ++t) {
        if (t < NPG / TILE - 1) {
#pragma unroll
            for (int i = 0; i < 4; ++i)
                pre[i] = sg[(t + 1) * TILE + tid + 256 * i];
        }
        // suffix = (global candidate index k = t*64+s) << 4 | ql
        unsigned suff = ((unsigned)(t << 10)) | (unsigned)ql;
#pragma unroll 4
        for (int s = 0; s < TILE / NSPLIT; ++s) {
            const float4 sj = sl[NSPLIT * s + ql];   // 16 distinct b128: conflict-free
            {
                const float dx = siA.x - sj.x, dy = siA.y - sj.y;
                const float dz = siA.z - sj.z, dw = siA.w - sj.w;
                const float d2 = fmaf(dx, dx, fmaf(dy, dy, fmaf(dz, dz, dw * dw)));
                ins4u(kA, (__float_as_uint(d2) & TRUNCM) | suff);
            }
            {
                const float dx = siB.x - sj.x, dy = siB.y - sj.y;
                const float dz = siB.z - sj.z, dw = siB.w - sj.w;
                const float d2 = fmaf(dx, dx, fmaf(dy, dy, fmaf(dz, dz, dw * dw)));
                ins4u(kB, (__float_as_uint(d2) & TRUNCM) | suff);
            }
            suff += 16u;                              // k increments by 1
        }
        if (t < NPG / TILE - 1) {
            __syncthreads();
#pragma unroll
            for (int i = 0; i < 4; ++i) sl[tid + 256 * i] = pre[i];
            __syncthreads();
        }
    }

    // ---- node A merge ----
    {
        unsigned md[8];
        md[0] = kA[0]; md[1] = kA[1]; md[2] = kA[2]; md[3] = kA[3];
        md[4] = (unsigned)__shfl_xor((int)kA[3], 1);
        md[5] = (unsigned)__shfl_xor((int)kA[2], 1);
        md[6] = (unsigned)__shfl_xor((int)kA[1], 1);
        md[7] = (unsigned)__shfl_xor((int)kA[0], 1);
        clean8u(md);                    // desc+asc bitonic -> sorted desc (all 8 kept)
        merge8u(md, 2);
        merge8u(md, 4);
        merge8u(md, 8);

        const unsigned truncW = md[0] & TRUNCM;
        int ci = 0;
#pragma unroll
        for (int r = 0; r < 4; ++r) ci += ((kA[r] & TRUNCM) <= truncW) ? 1 : 0;
        int v = ci + ((ci == 4) ? 256 : 0);
#pragma unroll
        for (int m = 1; m <= 8; m <<= 1) v += __shfl_xor(v, m);
        const bool flag = ((v & 0xFF) > 8) || ((v >> 8) != 0);

        unsigned ks = md[0];
#pragma unroll
        for (int r = 1; r < 8; ++r) { const bool p = (ql == r); ks = p ? md[r] : ks; }
        if (ql < 8)
            knnj[(size_t)nA * 8 + ql] = (int)(((ks >> 4) & 0xFFu) * 16u + (ks & 0xFu));
        if (ql == 0 && flag) {
            const int slot = atomicAdd(fcnt, 1);
            flist[slot] = nA;
        }
    }

    // ---- node B merge ----
    {
        unsigned md[8];
        md[0] = kB[0]; md[1] = kB[1]; md[2] = kB[2]; md[3] = kB[3];
        md[4] = (unsigned)__shfl_xor((int)kB[3], 1);
        md[5] = (unsigned)__shfl_xor((int)kB[2], 1);
        md[6] = (unsigned)__shfl_xor((int)kB[1], 1);
        md[7] = (unsigned)__shfl_xor((int)kB[0], 1);
        clean8u(md);
        merge8u(md, 2);
        merge8u(md, 4);
        merge8u(md, 8);

        const unsigned truncW = md[0] & TRUNCM;
        int ci = 0;
#pragma unroll
        for (int r = 0; r < 4; ++r) ci += ((kB[r] & TRUNCM) <= truncW) ? 1 : 0;
        int v = ci + ((ci == 4) ? 256 : 0);
#pragma unroll
        for (int m = 1; m <= 8; m <<= 1) v += __shfl_xor(v, m);
        const bool flag = ((v & 0xFF) > 8) || ((v >> 8) != 0);

        unsigned ks = md[0];
#pragma unroll
        for (int r = 1; r < 8; ++r) { const bool p = (ql == r); ks = p ? md[r] : ks; }
        if (ql < 8)
            knnj[(size_t)nB * 8 + ql] = (int)(((ks >> 4) & 0xFFu) * 16u + (ks & 0xFu));
        if (ql == 0 && flag) {
            const int slot = atomicAdd(fcnt, 1);
            flist[slot] = nB;
        }
    }
}

// ---------------------------------------------------------------------------
// Fixup: exact (d,j) rescan of the compacted flagged-node list.
// ---------------------------------------------------------------------------
__global__ __launch_bounds__(256, 4) void grav_fix(
        const float* __restrict__ s_buf,
        int* __restrict__ knnj,
        const int* __restrict__ fcnt, const int* __restrict__ flist) {
    const int cnt = fcnt[0];
    const int ql  = threadIdx.x & 15;
    const int ngroups = gridDim.x * 16;

    for (int idx = blockIdx.x * 16 + (threadIdx.x >> 4); idx < cnt; idx += ngroups) {
        const int node = flist[idx];
        const int gbase = node & ~(NPG - 1);
        const float4 si = ((const float4*)s_buf)[node];
        const float4* __restrict__ sg = (const float4*)s_buf + gbase;

        float fd[8]; int fj[8];
#pragma unroll
        for (int r = 0; r < 8; ++r) { fd[r] = FBIG; fj[r] = 0; }
#pragma unroll 4
        for (int k = 0; k < NPG / NSPLIT; ++k) {
            const int j = NSPLIT * k + ql;
            const float4 sj = sg[j];
            const float dx = si.x - sj.x, dy = si.y - sj.y;
            const float dz = si.z - sj.z, dw = si.w - sj.w;
            const float d2 = fmaf(dx, dx, fmaf(dy, dy, fmaf(dz, dz, dw * dw)));
            ins8(fd, fj, d2, j);
        }
        merge8(fd, fj, 1);
        merge8(fd, fj, 2);
        merge8(fd, fj, 4);
        merge8(fd, fj, 8);

        int js = fj[0];
#pragma unroll
        for (int r = 1; r < 8; ++r) { const bool p = (ql == r); js = p ? fj[r] : js; }
        if (ql < 8) knnj[(size_t)node * 8 + ql] = js;
    }
}

// ---------------------------------------------------------------------------
// Gather: recompute exact d2 from s (bit-identical chain), aggregate, fused
// output GEMM. 64 nodes/block, 4 lanes/node.
// ---------------------------------------------------------------------------
template <int ELD, bool TOUT>
__global__ __launch_bounds__(256, 4) void grav_gather(
        const float* __restrict__ emb_in,
        const float* __restrict__ s_buf,
        const float* __restrict__ h_buf,
        const int* __restrict__ knnj,
        const float* __restrict__ Wo, const float* __restrict__ bo,
        float* __restrict__ out) {
    __shared__ float wot[EMB * 81];       // Wo^T, rows padded 78 -> 81
    __shared__ float bol[EMB];
    __shared__ float cc[64][49];          // per-node mean @0, max @24

    const int tid = threadIdx.x;
    const int q   = tid & 3;
    const int nl  = tid >> 2;
    const int node = blockIdx.x * 64 + nl;
    const int gbase = node & ~(NPG - 1);

    for (int t = tid; t < CONCAT * EMB; t += 256) {
        const int r = t / EMB, c = t % EMB;
        wot[c * 81 + r] = Wo[t];
    }
    if (tid < EMB) bol[tid] = bo[tid];

    const float4 si = ((const float4*)s_buf)[node];
    const int ja = knnj[(size_t)node * 8 + q];
    const int jb = knnj[(size_t)node * 8 + 4 + q];
    const float4 sja = ((const float4*)s_buf)[gbase + ja];
    const float4 sjb = ((const float4*)s_buf)[gbase + jb];
    float wa, wb;
    {
        const float dx = si.x - sja.x, dy = si.y - sja.y;
        const float dz = si.z - sja.z, dw = si.w - sja.w;
        wa = expf(-10.f * fmaf(dx, dx, fmaf(dy, dy, fmaf(dz, dz, dw * dw))));
    }
    {
        const float dx = si.x - sjb.x, dy = si.y - sjb.y;
        const float dz = si.z - sjb.z, dw = si.w - sjb.w;
        wb = expf(-10.f * fmaf(dx, dx, fmaf(dy, dy, fmaf(dz, dz, dw * dw))));
    }
    const float4* __restrict__ ha = (const float4*)(h_buf + (size_t)(gbase + ja) * HPAD);
    const float4* __restrict__ hb = (const float4*)(h_buf + (size_t)(gbase + jb) * HPAD);

#pragma unroll
    for (int ch = 0; ch < 6; ++ch) {
        const float4 qa = ha[ch], qb = hb[ch];
        float sx = fmaf(wa, qa.x, wb * qb.x), sy = fmaf(wa, qa.y, wb * qb.y);
        float sz = fmaf(wa, qa.z, wb * qb.z), sw = fmaf(wa, qa.w, wb * qb.w);
        float mx = fmaxf(wa * qa.x, wb * qb.x), my = fmaxf(wa * qa.y, wb * qb.y);
        float mz = fmaxf(wa * qa.z, wb * qb.z), mw = fmaxf(wa * qa.w, wb * qb.w);
#pragma unroll
        for (int m = 1; m <= 2; m <<= 1) {
            sx += __shfl_xor(sx, m); sy += __shfl_xor(sy, m);
            sz += __shfl_xor(sz, m); sw += __shfl_xor(sw, m);
            mx = fmaxf(mx, __shfl_xor(mx, m)); my = fmaxf(my, __shfl_xor(my, m));
            mz = fmaxf(mz, __shfl_xor(mz, m)); mw = fmaxf(mw, __shfl_xor(mw, m));
        }
        if (q == (ch & 3)) {
            cc[nl][ch * 4 + 0] = sx * 0.125f; cc[nl][ch * 4 + 1] = sy * 0.125f;
            cc[nl][ch * 4 + 2] = sz * 0.125f; cc[nl][ch * 4 + 3] = sw * 0.125f;
            cc[nl][24 + ch * 4 + 0] = mx; cc[nl][24 + ch * 4 + 1] = my;
            cc[nl][24 + ch * 4 + 2] = mz; cc[nl][24 + ch * 4 + 3] = mw;
        }
    }
    __syncthreads();

    float e[EMB];
    const float* __restrict__ erow = emb_in + (size_t)node * ELD;
    if constexpr (ELD == 34) {
#pragma unroll
        for (int i = 0; i < 17; ++i) {
            const float2 v = ((const float2*)erow)[i];
            e[2 * i] = v.x; e[2 * i + 1] = v.y;
        }
    } else {
#pragma unroll
        for (int i = 0; i < 8; ++i) {
            const float4 v = ((const float4*)erow)[i];
            e[4 * i] = v.x; e[4 * i + 1] = v.y; e[4 * i + 2] = v.z; e[4 * i + 3] = v.w;
        }
        const float2 v = ((const float2*)erow)[16];
        e[32] = v.x; e[33] = v.y;
    }

#pragma unroll
    for (int m = 0; m < 9; ++m) {
        const int c = q + 4 * m;
        if (c < EMB) {
            const float* __restrict__ wr = &wot[c * 81];
            float acc = bol[c];
#pragma unroll
            for (int r = 0; r < EMB; ++r)   acc = fmaf(e[r], wr[r], acc);
#pragma unroll
            for (int p = 0; p < P_DIM; ++p) acc = fmaf(cc[nl][p], wr[34 + p], acc);
#pragma unroll
            for (int p = 0; p < P_DIM; ++p) acc = fmaf(cc[nl][24 + p], wr[56 + p], acc);
            if constexpr (TOUT)
                out[(size_t)c * N_NODES + node] = acc;
            else
                out[(size_t)node * EPAD + c] = acc;
        }
    }
}

// ---------------------------------------------------------------------------
// Fused 3-head MLP v3: 128 rows/block (2 rows/thread) so the 16 scalar
// weight loads per k feed 32 fmas (2 indep chains). Block = 512 thr
// (8 waves x 16 cols). LDS ~71.6 KB -> 2 blocks/CU.
// ---------------------------------------------------------------------------
__global__ __launch_bounds__(512, 4) void heads_fused(
        const float* __restrict__ emb2T,   // [34][N]
        const float* __restrict__ xin,
        float* __restrict__ outp,
        const float* __restrict__ W0a, const float* __restrict__ b0a,
        const float* __restrict__ Wha, const float* __restrict__ bha,
        const float* __restrict__ Wfa, const float* __restrict__ bfa,
        const float* __restrict__ W0b, const float* __restrict__ b0b,
        const float* __restrict__ Whb, const float* __restrict__ bhb,
        const float* __restrict__ Wfb, const float* __restrict__ bfb,
        const float* __restrict__ W0c, const float* __restrict__ b0c,
        const float* __restrict__ Whc, const float* __restrict__ bhc,
        const float* __restrict__ Wfc, const float* __restrict__ bfc) {
    __shared__ float sA[WIDTH * ASTR];    // 67 KB act [126][128+pad]
    __shared__ float sWf[128 * WFSTR];    // 4.5 KB final weights, stride 9

    const int tid  = threadIdx.x;
    const int head = blockIdx.x % 3;
    const int rowbase = (blockIdx.x / 3) * 128;
    const int lane = tid & 63;            // rows lane and lane+64
    const int wave = __builtin_amdgcn_readfirstlane(tid >> 6);
    int colbase = wave * 16;
    if (colbase > WIDTH - 16) colbase = WIDTH - 16;   // wave 7: 110..125 (dup benign)

    const float* W0 = head == 0 ? W0a : head == 1 ? W0b : W0c;
    const float* b0 = head == 0 ? b0a : head == 1 ? b0b : b0c;
    const float* Wh = head == 0 ? Wha : head == 1 ? Whb : Whc;
    const float* bh = head == 0 ? bha : head == 1 ? bhb : bhc;
    const float* Wf = head == 0 ? Wfa : head == 1 ? Wfb : Wfc;
    const float* bf = head == 0 ? bfa : head == 1 ? bfb : bfc;
    const int odim  = head == 0 ? 8 : head == 1 ? 4 : 1;
    const size_t ooff = head == 0 ? 0
                      : head == 1 ? (size_t)N_NODES * 8 : (size_t)N_NODES * 12;

    // stage Wf (zero-padded, stride 9)
    for (int t = tid; t < 128 * 8; t += 512) {
        const int k = t >> 3, o = t & 7;
        sWf[k * WFSTR + o] = (k < WIDTH && o < odim) ? Wf[k * odim + o] : 0.f;
    }

    float accA[16], accB[16];

    // ---- L0: 34 -> 126 (inputs from global, coalesced) ----
#pragma unroll
    for (int o = 0; o < 16; ++o) { accA[o] = b0[colbase + o]; accB[o] = accA[o]; }
#pragma unroll 2
    for (int k = 0; k < EMB; ++k) {
        const float xa = emb2T[(size_t)k * N_NODES + rowbase + lane];
        const float xb = emb2T[(size_t)k * N_NODES + rowbase + lane + 64];
        const float* __restrict__ wr = W0 + (size_t)k * WIDTH + colbase;
#pragma unroll
        for (int o = 0; o < 16; ++o) {
            const float w = wr[o];
            accA[o] = fmaf(xa, w, accA[o]);
            accB[o] = fmaf(xb, w, accB[o]);
        }
    }
    __syncthreads();   // sWf staging complete
#pragma unroll
    for (int o = 0; o < 16; ++o) {
        sA[(colbase + o) * ASTR + lane]      = elu1(accA[o]);
        sA[(colbase + o) * ASTR + lane + 64] = elu1(accB[o]);
    }
    __syncthreads();

    // ---- L1: 126 -> 126 ----
#pragma unroll
    for (int o = 0; o < 16; ++o) { accA[o] = bh[colbase + o]; accB[o] = accA[o]; }
#pragma unroll 2
    for (int k = 0; k < WIDTH; ++k) {
        const float xa = sA[k * ASTR + lane];
        const float xb = sA[k * ASTR + lane + 64];
        const float* __restrict__ wr = Wh + (size_t)k * WIDTH + colbase;
#pragma unroll
        for (int o = 0; o < 16; ++o) {
            const float w = wr[o];
            accA[o] = fmaf(xa, w, accA[o]);
            accB[o] = fmaf(xb, w, accB[o]);
        }
    }
    __syncthreads();
#pragma unroll
    for (int o = 0; o < 16; ++o) {
        sA[(colbase + o) * ASTR + lane]      = elu1(accA[o]);
        sA[(colbase + o) * ASTR + lane + 64] = elu1(accB[o]);
    }
    __syncthreads();

    // ---- L2: 126 -> 126 ----
#pragma unroll
    for (int o = 0; o < 16; ++o) { accA[o] = bh[WIDTH + colbase + o]; accB[o] = accA[o]; }
#pragma unroll 2
    for (int k = 0; k < WIDTH; ++k) {
        const float xa = sA[k * ASTR + lane];
        const float xb = sA[k * ASTR + lane + 64];
        const float* __restrict__ wr = Wh + (size_t)(WIDTH + k) * WIDTH + colbase;
#pragma unroll
        for (int o = 0; o < 16; ++o) {
            const float w = wr[o];
            accA[o] = fmaf(xa, w, accA[o]);
            accB[o] = fmaf(xb, w, accB[o]);
        }
    }
    __syncthreads();
#pragma unroll
    for (int o = 0; o < 16; ++o) {
        sA[(colbase + o) * ASTR + lane]      = elu1(accA[o]);
        sA[(colbase + o) * ASTR + lane + 64] = elu1(accB[o]);
    }
    __syncthreads();

    // ---- final: lane-strided k (k = lane, lane+64), full-wave reduce ----
    // wave w owns rows w*16 .. w*16+15 of the 128-row tile.
#pragma unroll 2
    for (int r = 0; r < 16; ++r) {
        const int rowl = wave * 16 + r;
        const float xa0 = sA[lane * ASTR + rowl];
        const float xa1 = (lane + 64 < WIDTH) ? sA[(lane + 64) * ASTR + rowl] : 0.f;
        float pa[8];
#pragma unroll
        for (int o = 0; o < 8; ++o) {
            const float w0 = sWf[lane * WFSTR + o];
            const float w1 = sWf[(lane + 64) * WFSTR + o];
            pa[o] = fmaf(xa0, w0, xa1 * w1);
        }
#pragma unroll
        for (int m = 1; m <= 32; m <<= 1) {
#pragma unroll
            for (int o = 0; o < 8; ++o) pa[o] += __shfl_xor(pa[o], m);
        }
        if (lane < odim) {
            float v = pa[0];
#pragma unroll
            for (int o = 1; o < 8; ++o) { const bool p = (lane == o); v = p ? pa[o] : v; }
            v += bf[lane];
            const int grow = rowbase + rowl;
            if (head == 1) v += xin[(size_t)grow * D_IN + 1 + lane];
            outp[ooff + (size_t)grow * odim + lane] = v;
        }
    }
}

// ---------------------------------------------------------------------------
extern "C" void kernel_launch(void* const* d_in, const int* in_sizes, int n_in,
                              void* d_out, int out_size, void* d_ws, size_t ws_size,
                              hipStream_t stream) {
    (void)in_sizes; (void)n_in; (void)out_size;

    const float* x   = (const float*)d_in[0];
    const float* cWs = (const float*)d_in[1];
    const float* cbs = (const float*)d_in[2];
    const float* cWh = (const float*)d_in[3];
    const float* cbh = (const float*)d_in[4];
    const float* cWo = (const float*)d_in[5];
    const float* cbo = (const float*)d_in[6];
    const float* hW0[3] = {(const float*)d_in[7],  (const float*)d_in[13], (const float*)d_in[19]};
    const float* hb0[3] = {(const float*)d_in[8],  (const float*)d_in[14], (const float*)d_in[20]};
    const float* hWh[3] = {(const float*)d_in[9],  (const float*)d_in[15], (const float*)d_in[21]};
    const float* hbh[3] = {(const float*)d_in[10], (const float*)d_in[16], (const float*)d_in[22]};
    const float* hWf[3] = {(const float*)d_in[11], (const float*)d_in[17], (const float*)d_in[23]};
    const float* hbf[3] = {(const float*)d_in[12], (const float*)d_in[18], (const float*)d_in[24]};
    float* outp = (float*)d_out;
    float* ws = (float*)d_ws;

    // workspace layout (floats)
    const size_t OFF_S   = 0;
    const size_t OFF_H   = OFF_S   + (size_t)N_NODES * 4;
    const size_t OFF_E1  = OFF_H   + (size_t)N_NODES * HPAD;
    const size_t OFF_E2T = OFF_E1  + (size_t)N_NODES * EPAD;
    const size_t OFF_KS  = OFF_E2T + (size_t)EMB * N_NODES;
    const size_t WS_END  = OFF_KS  + (size_t)N_NODES * 10;
    if (ws_size < WS_END * sizeof(float)) return;

    float* s_buf  = ws + OFF_S;
    float* h_buf  = ws + OFF_H;
    float* emb1   = ws + OFF_E1;
    float* emb2T  = ws + OFF_E2T;
    int*   knnj   = (int*)(ws + OFF_KS);                     // N*8 ints
    int*   flist  = (int*)(ws + OFF_KS + (size_t)N_NODES * 8);  // N ints
    int*   fcnt   = (int*)(ws + OFF_KS + (size_t)N_NODES * 9);  // 1 int

    // ---- GravNet conv 1 (emb = x, row-major out) ----
    sh_kernel<<<256, 256, 0, stream>>>(x, D_IN, cWs, cbs, cWh, cbh, s_buf, h_buf, fcnt);
    grav_scan<<<2048, 256, 0, stream>>>(s_buf, knnj, fcnt, flist);
    grav_fix<<<256, 256, 0, stream>>>(s_buf, knnj, fcnt, flist);
    grav_gather<34, false><<<1024, 256, 0, stream>>>(x, s_buf, h_buf, knnj, cWo, cbo, emb1);

    // ---- GravNet conv 2 (transposed out for heads) ----
    sh_kernel<<<256, 256, 0, stream>>>(emb1, EPAD, cWs + EMB * S_DIM, cbs + S_DIM,
                                       cWh + EMB * P_DIM, cbh + P_DIM, s_buf, h_buf, fcnt);
    grav_scan<<<2048, 256, 0, stream>>>(s_buf, knnj, fcnt, flist);
    grav_fix<<<256, 256, 0, stream>>>(s_buf, knnj, fcnt, flist);
    grav_gather<36, true><<<1024, 256, 0, stream>>>(emb1, s_buf, h_buf, knnj,
                                                    cWo + CONCAT * EMB, cbo + EMB, emb2T);

    // ---- heads: one fused dispatch for all 3 MLPs, 128 rows/block ----
    heads_fused<<<1536, 512, 0, stream>>>(
        emb2T, x, outp,
        hW0[0], hb0[0], hWh[0], hbh[0], hWf[0], hbf[0],
        hW0[1], hb0[1], hWh[1], hbh[1], hWf[1], hbf[1],
        hW0[2], hb0[2], hWh[2], hbh[2], hWf[2], hbf[2]);
}

// Round 11
// 645.205 us; speedup vs baseline: 1.5531x; 1.2027x over previous
//
#include <hip/hip_runtime.h>
#include <math.h>

#define N_NODES 65536
#define NPG     4096
#define D_IN    34
#define EMB     34
#define S_DIM   4
#define P_DIM   22
#define CONCAT  78      // EMB + 2*P_DIM
#define WIDTH   126
#define KNN     8
#define HPAD    24      // padded h row (22 -> 24)
#define EPAD    36      // padded emb row (34 -> 36)
#define TILE    1024    // j-tile staged in LDS
#define NSPLIT  16      // lanes per node
#define FBIG    3.4e38f
#define TRUNCM  0xFFFFF000u

// heads MFMA geometry
#define KSTR    136     // act LDS k-stride (x2B = 272B: 16B-aligned, ~2-way banks)
#define WSEG0   0       // L0 frag offset (ushorts)
#define WSEG1   8192    // L1
#define WSEG2   24576   // L2
#define WSEG3   40960   // Lf
#define WHEAD   43008   // per-head frag stride (ushorts)

__device__ __forceinline__ float elu1(float v) {
    return v > 0.f ? v : expm1f(v);
}

__device__ __forceinline__ bool lexlt(float da, int ja, float db, int jb) {
    return (da < db) || (da == db && ja < jb);
}

// bf16 RNE split helpers (weights/acts: no NaN/Inf)
__device__ __forceinline__ unsigned short f2bf(float v) {
    const unsigned u = __float_as_uint(v);
    return (unsigned short)((u + 0x7FFFu + ((u >> 16) & 1u)) >> 16);
}
__device__ __forceinline__ float bf2f(unsigned short h) {
    return __uint_as_float(((unsigned)h) << 16);
}

// ---- packed-key helpers (key = d2bits[31:12] | k[8b]<<4 | lane[4b]) ----
__device__ __forceinline__ void ins4u(unsigned (&k)[4], unsigned key) {
    unsigned c = min(key, k[0]);          // k[0] = worst kept (list sorted desc)
#pragma unroll
    for (int r = 3; r >= 1; --r) {
        const unsigned hi = max(k[r], c);
        k[r] = min(k[r], c);
        c = hi;
    }
    k[0] = c;
}

__device__ __forceinline__ void clean8u(unsigned (&k)[8]) {
#define CASU(i, j2) { const unsigned hi = max(k[i], k[j2]); \
    const unsigned lo = min(k[i], k[j2]); k[i] = hi; k[j2] = lo; }
    CASU(0,4) CASU(1,5) CASU(2,6) CASU(3,7)
    CASU(0,2) CASU(1,3) CASU(4,6) CASU(5,7)
    CASU(0,1) CASU(2,3) CASU(4,5) CASU(6,7)
#undef CASU
}

__device__ __forceinline__ void merge8u(unsigned (&k)[8], int m) {
    unsigned p[8];
#pragma unroll
    for (int i = 0; i < 8; ++i) p[i] = (unsigned)__shfl_xor((int)k[i], m);
#pragma unroll
    for (int i = 0; i < 8; ++i) k[i] = min(k[i], p[7 - i]);
    clean8u(k);
}

// ---- exact (d,j) helpers (fixup path) ----
__device__ __forceinline__ void ins8(float (&d)[8], int (&ix)[8], float dd, int jj) {
    const bool s0 = dd < d[0];
    d[0] = s0 ? dd : d[0]; ix[0] = s0 ? jj : ix[0];
#pragma unroll
    for (int r = 0; r < 7; ++r) {
        const bool s = d[r] < d[r + 1];
        const float a = s ? d[r + 1] : d[r], b = s ? d[r] : d[r + 1];
        const int   x = s ? ix[r + 1] : ix[r], y = s ? ix[r] : ix[r + 1];
        d[r] = a; d[r + 1] = b; ix[r] = x; ix[r + 1] = y;
    }
}

__device__ __forceinline__ void clean8(float (&md)[8], int (&mj)[8]) {
#define CASL(i, k) { const bool sw = lexlt(md[i], mj[i], md[k], mj[k]); \
    const float a = sw ? md[k] : md[i], b = sw ? md[i] : md[k]; \
    const int   x = sw ? mj[k] : mj[i], y = sw ? mj[i] : mj[k]; \
    md[i] = a; md[k] = b; mj[i] = x; mj[k] = y; }
    CASL(0,4) CASL(1,5) CASL(2,6) CASL(3,7)
    CASL(0,2) CASL(1,3) CASL(4,6) CASL(5,7)
    CASL(0,1) CASL(2,3) CASL(4,5) CASL(6,7)
#undef CASL
}

__device__ __forceinline__ void merge8(float (&md)[8], int (&mj)[8], int m) {
    float pd[8]; int pj[8];
#pragma unroll
    for (int i = 0; i < 8; ++i) { pd[i] = __shfl_xor(md[i], m); pj[i] = __shfl_xor(mj[i], m); }
#pragma unroll
    for (int i = 0; i < 8; ++i) {
        const bool lt = lexlt(md[i], mj[i], pd[7 - i], pj[7 - i]);
        const float nd = lt ? md[i] : pd[7 - i];
        const int   nj = lt ? mj[i] : pj[7 - i];
        md[i] = nd; mj[i] = nj;
    }
    clean8(md, mj);
}

// ---------------------------------------------------------------------------
// s = emb @ Ws + bs; h = emb @ Wh + bh (padded 24). Zeroes flag counter.
// ---------------------------------------------------------------------------
__global__ __launch_bounds__(256) void sh_kernel(
        const float* __restrict__ emb, int eld,
        const float* __restrict__ Ws, const float* __restrict__ bs,
        const float* __restrict__ Wh, const float* __restrict__ bh,
        float* __restrict__ s_out, float* __restrict__ h_out,
        int* __restrict__ fcnt) {
    if (blockIdx.x == 0 && threadIdx.x == 0) fcnt[0] = 0;

    __shared__ float lWs[EMB * S_DIM];
    __shared__ float lWh[EMB * P_DIM];
    __shared__ float lbs[S_DIM];
    __shared__ float lbh[P_DIM];
    for (int t = threadIdx.x; t < EMB * S_DIM; t += 256) lWs[t] = Ws[t];
    for (int t = threadIdx.x; t < EMB * P_DIM; t += 256) lWh[t] = Wh[t];
    if (threadIdx.x < S_DIM) lbs[threadIdx.x] = bs[threadIdx.x];
    if (threadIdx.x < P_DIM) lbh[threadIdx.x] = bh[threadIdx.x];
    __syncthreads();

    const int n = blockIdx.x * 256 + threadIdx.x;
    const float* __restrict__ row = emb + (size_t)n * eld;
    float e[EMB];
#pragma unroll
    for (int r = 0; r < EMB; ++r) e[r] = row[r];

    float s[S_DIM], h[P_DIM];
#pragma unroll
    for (int c = 0; c < S_DIM; ++c) s[c] = lbs[c];
#pragma unroll
    for (int c = 0; c < P_DIM; ++c) h[c] = lbh[c];
#pragma unroll
    for (int r = 0; r < EMB; ++r) {
        const float er = e[r];
#pragma unroll
        for (int c = 0; c < S_DIM; ++c) s[c] = fmaf(er, lWs[r * S_DIM + c], s[c]);
#pragma unroll
        for (int c = 0; c < P_DIM; ++c) h[c] = fmaf(er, lWh[r * P_DIM + c], h[c]);
    }
    ((float4*)s_out)[n] = make_float4(s[0], s[1], s[2], s[3]);
    float* __restrict__ hr = h_out + (size_t)n * HPAD;
#pragma unroll
    for (int c = 0; c < P_DIM; ++c) hr[c] = h[c];
}

// ---------------------------------------------------------------------------
// kNN scan (unchanged from R10): packed u32 keys, depth-4 lists, exact merge,
// sound truncation flag -> compacted worklist.
// ---------------------------------------------------------------------------
__global__ __launch_bounds__(256, 4) void grav_scan(
        const float* __restrict__ s_buf,
        int* __restrict__ knnj,
        int* __restrict__ fcnt, int* __restrict__ flist) {
    __shared__ float4 sl[TILE];           // 16 KB j-tile

    const int g     = blockIdx.x >> 7;
    const int chunk = blockIdx.x & 127;
    const int gbase = g * NPG;
    const int tid   = threadIdx.x;
    const int ql    = tid & 15;
    const int grp   = tid >> 4;
    const int nA    = gbase + chunk * 32 + grp * 2;
    const int nB    = nA + 1;

    const float4* __restrict__ sg = (const float4*)s_buf + gbase;
    float4 pre[4];
#pragma unroll
    for (int i = 0; i < 4; ++i) pre[i] = sg[tid + 256 * i];
    const float4 siA = ((const float4*)s_buf)[nA];
    const float4 siB = ((const float4*)s_buf)[nB];

    unsigned kA[4], kB[4];
#pragma unroll
    for (int r = 0; r < 4; ++r) { kA[r] = 0xFFFFFFFFu; kB[r] = 0xFFFFFFFFu; }

#pragma unroll
    for (int i = 0; i < 4; ++i) sl[tid + 256 * i] = pre[i];
    __syncthreads();

    for (int t = 0; t < NPG / TILE; ++t) {
        if (t < NPG / TILE - 1) {
#pragma unroll
            for (int i = 0; i < 4; ++i)
                pre[i] = sg[(t + 1) * TILE + tid + 256 * i];
        }
        unsigned suff = ((unsigned)(t << 10)) | (unsigned)ql;
#pragma unroll 4
        for (int s = 0; s < TILE / NSPLIT; ++s) {
            const float4 sj = sl[NSPLIT * s + ql];
            {
                const float dx = siA.x - sj.x, dy = siA.y - sj.y;
                const float dz = siA.z - sj.z, dw = siA.w - sj.w;
                const float d2 = fmaf(dx, dx, fmaf(dy, dy, fmaf(dz, dz, dw * dw)));
                ins4u(kA, (__float_as_uint(d2) & TRUNCM) | suff);
            }
            {
                const float dx = siB.x - sj.x, dy = siB.y - sj.y;
                const float dz = siB.z - sj.z, dw = siB.w - sj.w;
                const float d2 = fmaf(dx, dx, fmaf(dy, dy, fmaf(dz, dz, dw * dw)));
                ins4u(kB, (__float_as_uint(d2) & TRUNCM) | suff);
            }
            suff += 16u;
        }
        if (t < NPG / TILE - 1) {
            __syncthreads();
#pragma unroll
            for (int i = 0; i < 4; ++i) sl[tid + 256 * i] = pre[i];
            __syncthreads();
        }
    }

    // ---- node A merge ----
    {
        unsigned md[8];
        md[0] = kA[0]; md[1] = kA[1]; md[2] = kA[2]; md[3] = kA[3];
        md[4] = (unsigned)__shfl_xor((int)kA[3], 1);
        md[5] = (unsigned)__shfl_xor((int)kA[2], 1);
        md[6] = (unsigned)__shfl_xor((int)kA[1], 1);
        md[7] = (unsigned)__shfl_xor((int)kA[0], 1);
        clean8u(md);
        merge8u(md, 2);
        merge8u(md, 4);
        merge8u(md, 8);

        const unsigned truncW = md[0] & TRUNCM;
        int ci = 0;
#pragma unroll
        for (int r = 0; r < 4; ++r) ci += ((kA[r] & TRUNCM) <= truncW) ? 1 : 0;
        int v = ci + ((ci == 4) ? 256 : 0);
#pragma unroll
        for (int m = 1; m <= 8; m <<= 1) v += __shfl_xor(v, m);
        const bool flag = ((v & 0xFF) > 8) || ((v >> 8) != 0);

        unsigned ks = md[0];
#pragma unroll
        for (int r = 1; r < 8; ++r) { const bool p = (ql == r); ks = p ? md[r] : ks; }
        if (ql < 8)
            knnj[(size_t)nA * 8 + ql] = (int)(((ks >> 4) & 0xFFu) * 16u + (ks & 0xFu));
        if (ql == 0 && flag) {
            const int slot = atomicAdd(fcnt, 1);
            flist[slot] = nA;
        }
    }

    // ---- node B merge ----
    {
        unsigned md[8];
        md[0] = kB[0]; md[1] = kB[1]; md[2] = kB[2]; md[3] = kB[3];
        md[4] = (unsigned)__shfl_xor((int)kB[3], 1);
        md[5] = (unsigned)__shfl_xor((int)kB[2], 1);
        md[6] = (unsigned)__shfl_xor((int)kB[1], 1);
        md[7] = (unsigned)__shfl_xor((int)kB[0], 1);
        clean8u(md);
        merge8u(md, 2);
        merge8u(md, 4);
        merge8u(md, 8);

        const unsigned truncW = md[0] & TRUNCM;
        int ci = 0;
#pragma unroll
        for (int r = 0; r < 4; ++r) ci += ((kB[r] & TRUNCM) <= truncW) ? 1 : 0;
        int v = ci + ((ci == 4) ? 256 : 0);
#pragma unroll
        for (int m = 1; m <= 8; m <<= 1) v += __shfl_xor(v, m);
        const bool flag = ((v & 0xFF) > 8) || ((v >> 8) != 0);

        unsigned ks = md[0];
#pragma unroll
        for (int r = 1; r < 8; ++r) { const bool p = (ql == r); ks = p ? md[r] : ks; }
        if (ql < 8)
            knnj[(size_t)nB * 8 + ql] = (int)(((ks >> 4) & 0xFFu) * 16u + (ks & 0xFu));
        if (ql == 0 && flag) {
            const int slot = atomicAdd(fcnt, 1);
            flist[slot] = nB;
        }
    }
}

// ---------------------------------------------------------------------------
// Fixup: exact (d,j) rescan of the compacted flagged-node list.
// ---------------------------------------------------------------------------
__global__ __launch_bounds__(256, 4) void grav_fix(
        const float* __restrict__ s_buf,
        int* __restrict__ knnj,
        const int* __restrict__ fcnt, const int* __restrict__ flist) {
    const int cnt = fcnt[0];
    const int ql  = threadIdx.x & 15;
    const int ngroups = gridDim.x * 16;

    for (int idx = blockIdx.x * 16 + (threadIdx.x >> 4); idx < cnt; idx += ngroups) {
        const int node = flist[idx];
        const int gbase = node & ~(NPG - 1);
        const float4 si = ((const float4*)s_buf)[node];
        const float4* __restrict__ sg = (const float4*)s_buf + gbase;

        float fd[8]; int fj[8];
#pragma unroll
        for (int r = 0; r < 8; ++r) { fd[r] = FBIG; fj[r] = 0; }
#pragma unroll 4
        for (int k = 0; k < NPG / NSPLIT; ++k) {
            const int j = NSPLIT * k + ql;
            const float4 sj = sg[j];
            const float dx = si.x - sj.x, dy = si.y - sj.y;
            const float dz = si.z - sj.z, dw = si.w - sj.w;
            const float d2 = fmaf(dx, dx, fmaf(dy, dy, fmaf(dz, dz, dw * dw)));
            ins8(fd, fj, d2, j);
        }
        merge8(fd, fj, 1);
        merge8(fd, fj, 2);
        merge8(fd, fj, 4);
        merge8(fd, fj, 8);

        int js = fj[0];
#pragma unroll
        for (int r = 1; r < 8; ++r) { const bool p = (ql == r); js = p ? fj[r] : js; }
        if (ql < 8) knnj[(size_t)node * 8 + ql] = js;
    }
}

// ---------------------------------------------------------------------------
// Gather: recompute exact d2, aggregate, fused output GEMM. 64 nodes/block.
// ---------------------------------------------------------------------------
template <int ELD, bool TOUT>
__global__ __launch_bounds__(256, 4) void grav_gather(
        const float* __restrict__ emb_in,
        const float* __restrict__ s_buf,
        const float* __restrict__ h_buf,
        const int* __restrict__ knnj,
        const float* __restrict__ Wo, const float* __restrict__ bo,
        float* __restrict__ out) {
    __shared__ float wot[EMB * 81];       // Wo^T, rows padded 78 -> 81
    __shared__ float bol[EMB];
    __shared__ float cc[64][49];          // per-node mean @0, max @24

    const int tid = threadIdx.x;
    const int q   = tid & 3;
    const int nl  = tid >> 2;
    const int node = blockIdx.x * 64 + nl;
    const int gbase = node & ~(NPG - 1);

    for (int t = tid; t < CONCAT * EMB; t += 256) {
        const int r = t / EMB, c = t % EMB;
        wot[c * 81 + r] = Wo[t];
    }
    if (tid < EMB) bol[tid] = bo[tid];

    const float4 si = ((const float4*)s_buf)[node];
    const int ja = knnj[(size_t)node * 8 + q];
    const int jb = knnj[(size_t)node * 8 + 4 + q];
    const float4 sja = ((const float4*)s_buf)[gbase + ja];
    const float4 sjb = ((const float4*)s_buf)[gbase + jb];
    float wa, wb;
    {
        const float dx = si.x - sja.x, dy = si.y - sja.y;
        const float dz = si.z - sja.z, dw = si.w - sja.w;
        wa = expf(-10.f * fmaf(dx, dx, fmaf(dy, dy, fmaf(dz, dz, dw * dw))));
    }
    {
        const float dx = si.x - sjb.x, dy = si.y - sjb.y;
        const float dz = si.z - sjb.z, dw = si.w - sjb.w;
        wb = expf(-10.f * fmaf(dx, dx, fmaf(dy, dy, fmaf(dz, dz, dw * dw))));
    }
    const float4* __restrict__ ha = (const float4*)(h_buf + (size_t)(gbase + ja) * HPAD);
    const float4* __restrict__ hb = (const float4*)(h_buf + (size_t)(gbase + jb) * HPAD);

#pragma unroll
    for (int ch = 0; ch < 6; ++ch) {
        const float4 qa = ha[ch], qb = hb[ch];
        float sx = fmaf(wa, qa.x, wb * qb.x), sy = fmaf(wa, qa.y, wb * qb.y);
        float sz = fmaf(wa, qa.z, wb * qb.z), sw = fmaf(wa, qa.w, wb * qb.w);
        float mx = fmaxf(wa * qa.x, wb * qb.x), my = fmaxf(wa * qa.y, wb * qb.y);
        float mz = fmaxf(wa * qa.z, wb * qb.z), mw = fmaxf(wa * qa.w, wb * qb.w);
#pragma unroll
        for (int m = 1; m <= 2; m <<= 1) {
            sx += __shfl_xor(sx, m); sy += __shfl_xor(sy, m);
            sz += __shfl_xor(sz, m); sw += __shfl_xor(sw, m);
            mx = fmaxf(mx, __shfl_xor(mx, m)); my = fmaxf(my, __shfl_xor(my, m));
            mz = fmaxf(mz, __shfl_xor(mz, m)); mw = fmaxf(mw, __shfl_xor(mw, m));
        }
        if (q == (ch & 3)) {
            cc[nl][ch * 4 + 0] = sx * 0.125f; cc[nl][ch * 4 + 1] = sy * 0.125f;
            cc[nl][ch * 4 + 2] = sz * 0.125f; cc[nl][ch * 4 + 3] = sw * 0.125f;
            cc[nl][24 + ch * 4 + 0] = mx; cc[nl][24 + ch * 4 + 1] = my;
            cc[nl][24 + ch * 4 + 2] = mz; cc[nl][24 + ch * 4 + 3] = mw;
        }
    }
    __syncthreads();

    float e[EMB];
    const float* __restrict__ erow = emb_in + (size_t)node * ELD;
    if constexpr (ELD == 34) {
#pragma unroll
        for (int i = 0; i < 17; ++i) {
            const float2 v = ((const float2*)erow)[i];
            e[2 * i] = v.x; e[2 * i + 1] = v.y;
        }
    } else {
#pragma unroll
        for (int i = 0; i < 8; ++i) {
            const float4 v = ((const float4*)erow)[i];
            e[4 * i] = v.x; e[4 * i + 1] = v.y; e[4 * i + 2] = v.z; e[4 * i + 3] = v.w;
        }
        const float2 v = ((const float2*)erow)[16];
        e[32] = v.x; e[33] = v.y;
    }

#pragma unroll
    for (int m = 0; m < 9; ++m) {
        const int c = q + 4 * m;
        if (c < EMB) {
            const float* __restrict__ wr = &wot[c * 81];
            float acc = bol[c];
#pragma unroll
            for (int r = 0; r < EMB; ++r)   acc = fmaf(e[r], wr[r], acc);
#pragma unroll
            for (int p = 0; p < P_DIM; ++p) acc = fmaf(cc[nl][p], wr[34 + p], acc);
#pragma unroll
            for (int p = 0; p < P_DIM; ++p) acc = fmaf(cc[nl][24 + p], wr[56 + p], acc);
            if constexpr (TOUT)
                out[(size_t)c * N_NODES + node] = acc;
            else
                out[(size_t)node * EPAD + c] = acc;
        }
    }
}

// ---------------------------------------------------------------------------
// Weight prep: split fp32 weights into hi/lo bf16 and store in MFMA B-fragment
// order: pos(k,n) = ((ks*NT + nt)*64 + (ko>>3)*16 + (n&15))*8 + (ko&7),
// ks=k>>5, ko=k&31, nt=n>>4.  Segments: L0[64x128], L1[128x128], L2[128x128],
// Lf[128x16].  grid = (168, 3 heads); 168*256 == 43008 elems/head.
// ---------------------------------------------------------------------------
__global__ __launch_bounds__(256) void prep_wfrag(
        const float* __restrict__ W0a, const float* __restrict__ Wha, const float* __restrict__ Wfa,
        const float* __restrict__ W0b, const float* __restrict__ Whb, const float* __restrict__ Wfb,
        const float* __restrict__ W0c, const float* __restrict__ Whc, const float* __restrict__ Wfc,
        unsigned short* __restrict__ whi, unsigned short* __restrict__ wlo) {
    const int head = blockIdx.y;
    const int e = blockIdx.x * 256 + threadIdx.x;

    const float* W0 = head == 0 ? W0a : head == 1 ? W0b : W0c;
    const float* Wh = head == 0 ? Wha : head == 1 ? Whb : Whc;
    const float* Wf = head == 0 ? Wfa : head == 1 ? Wfb : Wfc;
    const int odim  = head == 0 ? 8 : head == 1 ? 4 : 1;

    int k, n, K, N, NT, ld, segbase;
    const float* src;
    if (e < WSEG1) {                  // L0: KPAD 64, NPAD 128
        const int e2 = e;      k = e2 >> 7; n = e2 & 127;
        K = EMB; N = WIDTH; NT = 8; ld = WIDTH; src = W0; segbase = WSEG0;
    } else if (e < WSEG2) {           // L1: KPAD 128, NPAD 128
        const int e2 = e - WSEG1; k = e2 >> 7; n = e2 & 127;
        K = WIDTH; N = WIDTH; NT = 8; ld = WIDTH; src = Wh; segbase = WSEG1;
    } else if (e < WSEG3) {           // L2
        const int e2 = e - WSEG2; k = e2 >> 7; n = e2 & 127;
        K = WIDTH; N = WIDTH; NT = 8; ld = WIDTH; src = Wh + WIDTH * WIDTH; segbase = WSEG2;
    } else {                          // Lf: KPAD 128, NPAD 16
        const int e2 = e - WSEG3; k = e2 >> 4; n = e2 & 15;
        K = WIDTH; N = odim; NT = 1; ld = odim; src = Wf; segbase = WSEG3;
    }

    const float val = (k < K && n < N) ? src[k * ld + n] : 0.f;
    const unsigned short h = f2bf(val);
    const unsigned short l = f2bf(val - bf2f(h));

    const int ks = k >> 5, ko = k & 31, nt = n >> 4;
    const int pos = (((ks * NT + nt) * 64) + ((ko >> 3) * 16) + (n & 15)) * 8 + (ko & 7);
    whi[(size_t)head * WHEAD + segbase + pos] = h;
    wlo[(size_t)head * WHEAD + segbase + pos] = l;
}

// ---------------------------------------------------------------------------
// Fused 3-head MLP on MFMA, split-bf16 (x=xh+xl, W=Wh+Wl; 3 mfma per pair ->
// ~fp32 accuracy). Block = 256 thr (4 waves), 64 rows x 128 cols; wave w owns
// N-tiles 2w, 2w+1. Act tiles (hi/lo bf16) live in LDS; weights read from
// fragment-ordered global (coalesced, L2-resident). Final layer: K split
// across waves + LDS reduce. grid = 1024 row-blocks * 3 heads.
// Fragment layouts (16x16x32 bf16): A: lane l -> A[l&15][(l>>4)*8+j];
// B: lane l -> B[(l>>4)*8+j][l&15]; C/D: col=lane&15, row=(lane>>4)*4+reg.
// ---------------------------------------------------------------------------
typedef __attribute__((ext_vector_type(8))) short bf8;
typedef __attribute__((ext_vector_type(4))) float f32x4;

__global__ __launch_bounds__(256, 3) void heads_mfma(
        const float* __restrict__ emb2T,   // [34][N] fp32
        const float* __restrict__ xin,
        float* __restrict__ outp,
        const unsigned short* __restrict__ whi,
        const unsigned short* __restrict__ wlo,
        const float* __restrict__ b0a, const float* __restrict__ bha, const float* __restrict__ bfa,
        const float* __restrict__ b0b, const float* __restrict__ bhb, const float* __restrict__ bfb,
        const float* __restrict__ b0c, const float* __restrict__ bhc, const float* __restrict__ bfc) {
    __shared__ unsigned short aH[64 * KSTR];   // 17 KB act hi
    __shared__ unsigned short aL[64 * KSTR];   // 17 KB act lo
    __shared__ float pf[4 * 64 * 16];          // 16 KB final partials

    const int tid  = threadIdx.x;
    const int head = blockIdx.x % 3;
    const int rowbase = (blockIdx.x / 3) * 64;
    const int w = tid >> 6;                    // wave 0..3
    const int l = tid & 63;

    const unsigned short* WH = whi + (size_t)head * WHEAD;
    const unsigned short* WL = wlo + (size_t)head * WHEAD;
    const float* b0 = head == 0 ? b0a : head == 1 ? b0b : b0c;
    const float* bh = head == 0 ? bha : head == 1 ? bhb : bhc;
    const float* bf = head == 0 ? bfa : head == 1 ? bfb : bfc;
    const int odim  = head == 0 ? 8 : head == 1 ? 4 : 1;
    const size_t ooff = head == 0 ? 0
                      : head == 1 ? (size_t)N_NODES * 8 : (size_t)N_NODES * 12;

    // ---- stage L0 input (k = 0..33, zero-pad to 64) as hi/lo bf16 ----
    for (int t = tid; t < 64 * 64; t += 256) {
        const int r = t & 63, k = t >> 6;
        const float v = (k < EMB) ? emb2T[(size_t)k * N_NODES + rowbase + r] : 0.f;
        const unsigned short h = f2bf(v);
        aH[r * KSTR + k] = h;
        aL[r * KSTR + k] = f2bf(v - bf2f(h));
    }
    __syncthreads();

    const int lm = l & 15;        // fragment row/col within tile
    const int lk = (l >> 4) * 8;  // fragment k-offset

    // ================= L0 (K=64), L1, L2 (K=128) =================
#pragma unroll
    for (int layer = 0; layer < 3; ++layer) {
        const int KS = (layer == 0) ? 2 : 4;
        const int seg = (layer == 0) ? WSEG0 : (layer == 1) ? WSEG1 : WSEG2;
        const float* bias = (layer == 0) ? b0 : (layer == 1) ? bh : bh + WIDTH;

        f32x4 acc[4][2];
#pragma unroll
        for (int nt2 = 0; nt2 < 2; ++nt2) {
            const int col = (w * 2 + nt2) * 16 + lm;
            const float bv = (col < WIDTH) ? bias[col] : 0.f;
#pragma unroll
            for (int mt = 0; mt < 4; ++mt)
                acc[mt][nt2] = f32x4{bv, bv, bv, bv};
        }

        for (int ks = 0; ks < KS; ++ks) {
            bf8 bh0, bh1, bl0, bl1;
            {
                const size_t o0 = ((size_t)(ks * 8 + w * 2 + 0) * 64 + l) * 8;
                const size_t o1 = ((size_t)(ks * 8 + w * 2 + 1) * 64 + l) * 8;
                bh0 = *(const bf8*)(WH + seg + o0);
                bh1 = *(const bf8*)(WH + seg + o1);
                bl0 = *(const bf8*)(WL + seg + o0);
                bl1 = *(const bf8*)(WL + seg + o1);
            }
#pragma unroll
            for (int mt = 0; mt < 4; ++mt) {
                const int aoff = (mt * 16 + lm) * KSTR + ks * 32 + lk;
                const bf8 ah = *(const bf8*)&aH[aoff];
                const bf8 al = *(const bf8*)&aL[aoff];
                acc[mt][0] = __builtin_amdgcn_mfma_f32_16x16x32_bf16(ah, bh0, acc[mt][0], 0, 0, 0);
                acc[mt][0] = __builtin_amdgcn_mfma_f32_16x16x32_bf16(ah, bl0, acc[mt][0], 0, 0, 0);
                acc[mt][0] = __builtin_amdgcn_mfma_f32_16x16x32_bf16(al, bh0, acc[mt][0], 0, 0, 0);
                acc[mt][1] = __builtin_amdgcn_mfma_f32_16x16x32_bf16(ah, bh1, acc[mt][1], 0, 0, 0);
                acc[mt][1] = __builtin_amdgcn_mfma_f32_16x16x32_bf16(ah, bl1, acc[mt][1], 0, 0, 0);
                acc[mt][1] = __builtin_amdgcn_mfma_f32_16x16x32_bf16(al, bh1, acc[mt][1], 0, 0, 0);
            }
        }
        __syncthreads();   // all act reads done before overwrite

        // elu + split -> next act tile (act[row][col] = next layer's [row][k])
#pragma unroll
        for (int mt = 0; mt < 4; ++mt) {
#pragma unroll
            for (int nt2 = 0; nt2 < 2; ++nt2) {
                const int col = (w * 2 + nt2) * 16 + lm;
#pragma unroll
                for (int r = 0; r < 4; ++r) {
                    const int row = mt * 16 + (l >> 4) * 4 + r;
                    const float v = elu1(acc[mt][nt2][r]);
                    const unsigned short h = f2bf(v);
                    aH[row * KSTR + col] = h;
                    aL[row * KSTR + col] = f2bf(v - bf2f(h));
                }
            }
        }
        __syncthreads();
    }

    // ================= Lf: K=128 split across waves (ks = w) =================
    {
        f32x4 facc[4];
#pragma unroll
        for (int mt = 0; mt < 4; ++mt) facc[mt] = f32x4{0.f, 0.f, 0.f, 0.f};

        const int ks = w;
        const size_t o0 = ((size_t)(ks * 1 + 0) * 64 + l) * 8;
        const bf8 bh0 = *(const bf8*)(WH + WSEG3 + o0);
        const bf8 bl0 = *(const bf8*)(WL + WSEG3 + o0);
#pragma unroll
        for (int mt = 0; mt < 4; ++mt) {
            const int aoff = (mt * 16 + lm) * KSTR + ks * 32 + lk;
            const bf8 ah = *(const bf8*)&aH[aoff];
            const bf8 al = *(const bf8*)&aL[aoff];
            facc[mt] = __builtin_amdgcn_mfma_f32_16x16x32_bf16(ah, bh0, facc[mt], 0, 0, 0);
            facc[mt] = __builtin_amdgcn_mfma_f32_16x16x32_bf16(ah, bl0, facc[mt], 0, 0, 0);
            facc[mt] = __builtin_amdgcn_mfma_f32_16x16x32_bf16(al, bh0, facc[mt], 0, 0, 0);
        }
#pragma unroll
        for (int mt = 0; mt < 4; ++mt) {
#pragma unroll
            for (int r = 0; r < 4; ++r) {
                const int row = mt * 16 + (l >> 4) * 4 + r;
                pf[(w * 64 + row) * 16 + lm] = facc[mt][r];
            }
        }
        __syncthreads();

        const int sh = head == 0 ? 3 : head == 1 ? 2 : 0;
        for (int e = tid; e < 64 * odim; e += 256) {
            const int row = e >> sh;
            const int o = e & (odim - 1);
            float v = pf[(0 * 64 + row) * 16 + o] + pf[(1 * 64 + row) * 16 + o]
                    + pf[(2 * 64 + row) * 16 + o] + pf[(3 * 64 + row) * 16 + o];
            v += bf[o];
            const int grow = rowbase + row;
            if (head == 1) v += xin[(size_t)grow * D_IN + 1 + o];
            outp[ooff + (size_t)grow * odim + o] = v;
        }
    }
}

// ---------------------------------------------------------------------------
extern "C" void kernel_launch(void* const* d_in, const int* in_sizes, int n_in,
                              void* d_out, int out_size, void* d_ws, size_t ws_size,
                              hipStream_t stream) {
    (void)in_sizes; (void)n_in; (void)out_size;

    const float* x   = (const float*)d_in[0];
    const float* cWs = (const float*)d_in[1];
    const float* cbs = (const float*)d_in[2];
    const float* cWh = (const float*)d_in[3];
    const float* cbh = (const float*)d_in[4];
    const float* cWo = (const float*)d_in[5];
    const float* cbo = (const float*)d_in[6];
    const float* hW0[3] = {(const float*)d_in[7],  (const float*)d_in[13], (const float*)d_in[19]};
    const float* hb0[3] = {(const float*)d_in[8],  (const float*)d_in[14], (const float*)d_in[20]};
    const float* hWh[3] = {(const float*)d_in[9],  (const float*)d_in[15], (const float*)d_in[21]};
    const float* hbh[3] = {(const float*)d_in[10], (const float*)d_in[16], (const float*)d_in[22]};
    const float* hWf[3] = {(const float*)d_in[11], (const float*)d_in[17], (const float*)d_in[23]};
    const float* hbf[3] = {(const float*)d_in[12], (const float*)d_in[18], (const float*)d_in[24]};
    float* outp = (float*)d_out;
    float* ws = (float*)d_ws;

    // workspace layout (floats)
    const size_t OFF_S   = 0;
    const size_t OFF_H   = OFF_S   + (size_t)N_NODES * 4;
    const size_t OFF_E1  = OFF_H   + (size_t)N_NODES * HPAD;
    const size_t OFF_E2T = OFF_E1  + (size_t)N_NODES * EPAD;
    const size_t OFF_KS  = OFF_E2T + (size_t)EMB * N_NODES;
    const size_t OFF_WH  = OFF_KS  + (size_t)N_NODES * 10;   // whi: 3*43008 ushorts
    const size_t OFF_WL  = OFF_WH  + (3 * WHEAD + 1) / 2;
    const size_t WS_END  = OFF_WL  + (3 * WHEAD + 1) / 2;
    if (ws_size < WS_END * sizeof(float)) return;

    float* s_buf  = ws + OFF_S;
    float* h_buf  = ws + OFF_H;
    float* emb1   = ws + OFF_E1;
    float* emb2T  = ws + OFF_E2T;
    int*   knnj   = (int*)(ws + OFF_KS);                        // N*8 ints
    int*   flist  = (int*)(ws + OFF_KS + (size_t)N_NODES * 8);  // N ints
    int*   fcnt   = (int*)(ws + OFF_KS + (size_t)N_NODES * 9);  // 1 int
    unsigned short* whi = (unsigned short*)(ws + OFF_WH);
    unsigned short* wlo = (unsigned short*)(ws + OFF_WL);

    // ---- prep: split+fragment-order head weights (independent of convs) ----
    prep_wfrag<<<dim3(168, 3), 256, 0, stream>>>(
        hW0[0], hWh[0], hWf[0], hW0[1], hWh[1], hWf[1], hW0[2], hWh[2], hWf[2],
        whi, wlo);

    // ---- GravNet conv 1 (emb = x, row-major out) ----
    sh_kernel<<<256, 256, 0, stream>>>(x, D_IN, cWs, cbs, cWh, cbh, s_buf, h_buf, fcnt);
    grav_scan<<<2048, 256, 0, stream>>>(s_buf, knnj, fcnt, flist);
    grav_fix<<<256, 256, 0, stream>>>(s_buf, knnj, fcnt, flist);
    grav_gather<34, false><<<1024, 256, 0, stream>>>(x, s_buf, h_buf, knnj, cWo, cbo, emb1);

    // ---- GravNet conv 2 (transposed out for heads) ----
    sh_kernel<<<256, 256, 0, stream>>>(emb1, EPAD, cWs + EMB * S_DIM, cbs + S_DIM,
                                       cWh + EMB * P_DIM, cbh + P_DIM, s_buf, h_buf, fcnt);
    grav_scan<<<2048, 256, 0, stream>>>(s_buf, knnj, fcnt, flist);
    grav_fix<<<256, 256, 0, stream>>>(s_buf, knnj, fcnt, flist);
    grav_gather<36, true><<<1024, 256, 0, stream>>>(emb1, s_buf, h_buf, knnj,
                                                    cWo + CONCAT * EMB, cbo + EMB, emb2T);

    // ---- heads: MFMA split-bf16, one dispatch for all 3 heads ----
    heads_mfma<<<3072, 256, 0, stream>>>(
        emb2T, x, outp, whi, wlo,
        hb0[0], hbh[0], hbf[0],
        hb0[1], hbh[1], hbf[1],
        hb0[2], hbh[2], hbf[2]);
}